// Round 8
// baseline (104.777 us; speedup 1.0000x reference)
//
#include <hip/hip_runtime.h>
#include <math.h>

// ---- problem constants ----
#define WAV_N     262144
#define HOP       128
#define MIN_WIN   16699
#define LEFT      24418            // (65536 - 16699)/2
#define T_FRAMES  2049
#define N_BINS    96
#define N_CQCC    20
#define F_COMP    192              // 96 bins x {lo,hi}
#define NF        576              // 192 comps x 3 Hann planes
#define NBLK      2179             // 128-sample chunks covering padded signal
#define NBP       2240             // padded b-dim for QFP rows (= 70*32)
#define PARTLEN   59               // 16699 - 130*128
#define FULLBLK   130
#define XS_VALID  278843           // 2048*128 + 16699
#define TWOPI     6.283185307179586f

// ---- chunk kernel tiling (r18, kept): 1260 blocks (140 x 9), 256 thr = 64f x 4wg ----
// r18 broadcast-read CONFIRMED (-1.9us): wave-uniform b-group -> each ds_read_b128
// is one address broadcast to 64 lanes. k_chunk now ~7.5us, near its 6.3us VALU
// floor; more b/thread forbidden (r11/r13/r17: wave count is load-bearing). CLOSED.
#define BT   16
#define FTW  64
#define AST  20                    // row stride (floats); 80B rows, b128 reads 16B-aligned

// ---- workspace layout (bytes) ----
#define WS_QFP  0                  // 576*2240*16 = 20,643,840  float4(qf.re,qf.im,qp.re,qp.im)
#define WS_V    20643840           // folded V: 192*2056*8 = 3,158,016
#define WS_CQ   30117888           // 2049*20*4 =    163,920
#define WS_SUMS 30281808           // 40 doubles
#define VTP     2056               // V row stride (float2 units)

// f = plane*192 + c; c = bin*2 + hi; replicate reference f32 arithmetic for floor()
__device__ __forceinline__ void f_to_fi_sigma(int f, int& fi, int& sigma) {
    int plane = f / 192;
    int c = f - plane * 192;
    int bin = c >> 1, hi = c & 1;
    float e    = (float)bin / 24.0f;
    float fb   = 32.7f * exp2f(e);
    float idxf = fb / 8000.0f * 32768.0f;
    fi = (int)idxf + hi;
    sigma = (plane == 0) ? 0 : (plane == 1 ? 1 : -1);
}

__device__ __forceinline__ void make_rot(int fi, int sg, float& Dr, float& Di) {
    float fr = (float)fi * (1.0f / 65536.0f) - (float)sg * (1.0f / (float)MIN_WIN);
    fr -= rintf(fr);
    float sn, cs; __sincosf(TWOPI * fr, &sn, &cs);
    Dr = cs; Di = -sn;
}

// one j-step: 8 fma (4 b x re/im) + rotator update. Identical op order to r12/r16.
#define STEP(a0_, a1_, a2_, a3_) do {                                   \
    xr[0] = fmaf((a0_), Wr, xr[0]); xi[0] = fmaf((a0_), Wi, xi[0]);     \
    xr[1] = fmaf((a1_), Wr, xr[1]); xi[1] = fmaf((a1_), Wi, xi[1]);     \
    xr[2] = fmaf((a2_), Wr, xr[2]); xi[2] = fmaf((a2_), Wi, xi[2]);     \
    xr[3] = fmaf((a3_), Wr, xr[3]); xi[3] = fmaf((a3_), Wi, xi[3]);     \
    float wr_ = Wr;                                                     \
    Wr = wr_ * Dr - Wi * Di;                                            \
    Wi = wr_ * Di + Wi * Dr; } while (0)

// QFP[f][b] = (qf, qp): qf = e^{-i w0} sum_{j<128} xs[128b+j] E[j][f], qp = j<59 version
__global__ __launch_bounds__(256) void k_chunk(const float* __restrict__ wav,
                                               float4* __restrict__ QFP) {
    __shared__ __align__(16) float A_lds[128 * AST];   // 10,240 B
    int tid = threadIdx.x;
    int b0 = blockIdx.x * BT;
    int f0 = blockIdx.y * FTW;

    // stage 16b x 128j tile (256 thr x 8 elems)
    {
        int sbase = 128 * b0;
        #pragma unroll
        for (int k = 0; k < 8; ++k) {
            int m = k * 256 + tid;
            int j = m & 127, bl = m >> 7;              // bl 0..15
            int s = sbase + m;
            float v = 0.0f;
            if (s < XS_VALID) {
                int w = s - 8350;                      // s + LEFT - 32768
                if (w < 0) w = -w;
                if (w >= WAV_N) w = 2 * WAV_N - 2 - w;
                v = wav[w];
            }
            A_lds[j * AST + bl] = v;
        }
    }

    int fl = tid & 63;
    int bg = tid >> 6;                             // wave id 0..3 (uniform per wave)
    int bl0 = bg * 4;
    int bb = b0 + bl0;

    int f = f0 + fl;
    int fi, sg; f_to_fi_sigma(f, fi, sg);
    float Dr, Di; make_rot(fi, sg, Dr, Di);
    float Wr = 1.0f, Wi = 0.0f;

    float xr[4] = {0, 0, 0, 0}, xi[4] = {0, 0, 0, 0};
    float pr[4], pi[4];

    __syncthreads();

    #pragma unroll 4
    for (int j = 0; j < PARTLEN; ++j) {
        float4 a = *(const float4*)&A_lds[j * AST + bl0];   // 1 addr, 64-lane broadcast
        STEP(a.x, a.y, a.z, a.w);
    }
    #pragma unroll
    for (int i = 0; i < 4; ++i) { pr[i] = xr[i]; pi[i] = xi[i]; }
    #pragma unroll 4
    for (int j = PARTLEN; j < 128; ++j) {
        float4 a = *(const float4*)&A_lds[j * AST + bl0];
        STEP(a.x, a.y, a.z, a.w);
    }

    float4* dst = QFP + (size_t)f * NBP + bb;
    #pragma unroll
    for (int i = 0; i < 4; ++i) {
        int b = bb + i;
        unsigned ph = ((unsigned)fi * (unsigned)(LEFT + 128 * b)) & 65535u;
        float frf = (float)ph * (1.0f / 65536.0f)
                  - (float)sg * (float)((128 * b) % MIN_WIN) * (1.0f / (float)MIN_WIN);
        frf -= rintf(frf);
        float sn, cs; __sincosf(TWOPI * frf, &sn, &cs);
        dst[i] = make_float4(xr[i] * cs + xi[i] * sn,
                             xi[i] * cs - xr[i] * sn,
                             pr[i] * cs + pi[i] * sn,
                             pi[i] * cs - pr[i] * sn);
    }
}

// r19: one block per c (192 blocks x 512 thr), 3 Hann planes SEQUENTIALLY through
// the same col LDS; per-plane rotated results held in registers (5 t-slots x 3
// planes x float2); write the FOLDED row once. Cuts V write 9.5->3.2 MB and
// k_cqt's fold read 9.5->3.2 MB. Per-plane scan/rotate math verbatim from r18;
// fold expression verbatim from r18's k_cqt -> bit-identical output.
#define SEG 5                      // 512*5 = 2560 >= 2179
__global__ __launch_bounds__(512) void k_scan(const float4* __restrict__ QFP,
                                              float2* __restrict__ V,
                                              double* __restrict__ sums) {
    __shared__ float4 col[NBLK];       // 34,864 B (reused per plane)
    __shared__ double2 wsum[8];
    int tid = threadIdx.x;
    int c = blockIdx.x;
    if (c == 0 && tid < 40) sums[tid] = 0.0;   // zero stats accumulators

    float2 rv[3][SEG];                 // per-plane rotated U, registers

    for (int p = 0; p < 3; ++p) {
        int f = p * 192 + c;
        const float4* g = QFP + (size_t)f * NBP;
        #pragma unroll
        for (int k = 0; k < SEG; ++k) {
            int idx = k * 512 + tid;
            if (idx < NBLK) col[idx] = g[idx];
        }
        __syncthreads();

        int s0 = tid * SEG, s1 = min(s0 + SEG, NBLK);
        double sr = 0.0, si = 0.0;
        for (int i = s0; i < s1; ++i) { sr += col[i].x; si += col[i].y; }
        double r = sr, im = si;
        #pragma unroll
        for (int off = 1; off < 64; off <<= 1) {
            double prx = __shfl_up(r, off);
            double piy = __shfl_up(im, off);
            if ((tid & 63) >= off) { r += prx; im += piy; }
        }
        if ((tid & 63) == 63) wsum[tid >> 6] = make_double2(r, im);
        __syncthreads();
        double basr = 0.0, basi = 0.0;
        int w = tid >> 6;
        for (int ww = 0; ww < w; ++ww) { basr += wsum[ww].x; basi += wsum[ww].y; }
        double gr = basr + r - sr, gi = basi + im - si;   // exclusive prefix at s0
        for (int i = s0; i < s1; ++i) {
            float qx = col[i].x, qy = col[i].y;
            col[i].x = (float)gr; col[i].y = (float)gi;
            gr += qx; gi += qy;
        }
        __syncthreads();

        int fi_, sg_; f_to_fi_sigma(f, fi_, sg_);
        #pragma unroll
        for (int k = 0; k < SEG; ++k) {
            int t = k * 512 + tid;
            float2 res = make_float2(0.f, 0.f);
            if (t < T_FRAMES) {
                float4 ca = col[t];
                float4 cb = col[t + FULLBLK];
                float ur = cb.x - ca.x + cb.z;
                float ui = cb.y - ca.y + cb.w;
                unsigned ph = ((unsigned)fi_ * 128u * (unsigned)t) & 65535u;
                float frf = (float)ph * (1.0f / 65536.0f)
                          - (float)sg_ * (float)((128 * t) % MIN_WIN) * (1.0f / (float)MIN_WIN);
                frf -= rintf(frf);
                float sn, cs;
                __sincosf(TWOPI * frf, &sn, &cs);
                res = make_float2(ur * cs - ui * sn, ur * sn + ui * cs);
            }
            rv[p][k] = res;
        }
        __syncthreads();   // protect col before next plane's staging
    }

    float2* vrow = V + (size_t)c * VTP;
    #pragma unroll
    for (int k = 0; k < SEG; ++k) {
        int t = k * 512 + tid;
        if (t < T_FRAMES) {
            float2 v0 = rv[0][k], v1 = rv[1][k], v2 = rv[2][k];
            vrow[t] = make_float2(0.5f * v0.x - 0.25f * (v1.x + v2.x),
                                  0.5f * v0.y - 0.25f * (v1.y + v2.y));
        }
    }
}

// 8 frames/block (257 blocks): read FOLDED V (1 row per c) -> power -> interp
// -> log -> DCT -> fp64 atomic stats partials
#define TF 8
__global__ __launch_bounds__(256) void k_cqt(const float2* __restrict__ V,
                                             float* __restrict__ cq,
                                             double* __restrict__ sums) {
    __shared__ float dctm[N_CQCC * N_BINS];     // 7680 B
    __shared__ float2 sc[F_COMP * TF];          // [c][tl], 12,288 B
    __shared__ float lg[N_BINS * TF];           // [b][tl], 3072 B
    __shared__ float cqv[N_CQCC * TF];          // [k][tl], 640 B
    int tid = threadIdx.x;
    int tb = blockIdx.x * TF;
    for (int idx = tid; idx < N_CQCC * N_BINS; idx += 256) {
        int k = idx / N_BINS, b = idx - k * N_BINS;
        dctm[idx] = cosf((float)M_PI * (float)(k * (2 * b + 1)) / 192.0f);
    }
    // load folded rows: idx = c*TF + tl; contiguous along t (64 B per row chunk)
    for (int idx = tid; idx < F_COMP * TF; idx += 256) {
        int c = idx / TF, tl = idx % TF;
        int t = tb + tl;
        float2 v = make_float2(0.f, 0.f);
        if (t < T_FRAMES) v = V[(size_t)c * VTP + t];
        sc[idx] = v;
    }
    __syncthreads();
    for (int idx = tid; idx < N_BINS * TF; idx += 256) {
        int b = idx / TF, tl = idx % TF;
        float2 lo = sc[(2 * b) * TF + tl];
        float2 hi = sc[(2 * b + 1) * TF + tl];
        float pl = lo.x * lo.x + lo.y * lo.y;
        float ph = hi.x * hi.x + hi.y * hi.y;
        float e    = (float)b / 24.0f;
        float fb   = 32.7f * exp2f(e);
        float idxf = fb / 8000.0f * 32768.0f;
        float alpha = idxf - (float)((int)idxf);
        float p = (1.0f - alpha) * pl + alpha * ph;
        lg[idx] = logf(fmaxf(p, 1e-8f));
    }
    __syncthreads();
    for (int idx = tid; idx < N_CQCC * TF; idx += 256) {
        int k = idx / TF, tl = idx % TF;
        int t = tb + tl;
        float s = 0.0f;
        #pragma unroll 4
        for (int b = 0; b < N_BINS; ++b) s += dctm[k * N_BINS + b] * lg[b * TF + tl];
        cqv[idx] = (t < T_FRAMES) ? s : 0.0f;
        if (t < T_FRAMES) cq[t * N_CQCC + k] = s;
    }
    __syncthreads();
    if (tid < N_CQCC) {
        double s1 = 0.0, s2 = 0.0;
        #pragma unroll
        for (int tl = 0; tl < TF; ++tl) {
            if (tb + tl < T_FRAMES) {
                double v = (double)cqv[tid * TF + tl];
                s1 += v; s2 += v * v;
            }
        }
        atomicAdd(&sums[tid], s1);
        atomicAdd(&sums[N_CQCC + tid], s2);
    }
}

__device__ __forceinline__ int clampT(int v) {
    return v < 0 ? 0 : (v > T_FRAMES - 1 ? T_FRAMES - 1 : v);
}

// normalize + delta + delta-delta; mean/inv derived inline from fp64 sums
__global__ void k_final(const float* __restrict__ cq, const double* __restrict__ sums,
                        float* __restrict__ out) {
    int gid = blockIdx.x * blockDim.x + threadIdx.x;
    if (gid >= T_FRAMES * N_CQCC) return;
    int t = gid / N_CQCC;
    int k = gid - t * N_CQCC;
    double S1 = sums[k], S2 = sums[N_CQCC + k];
    double md = S1 / (double)T_FRAMES;
    double var = (S2 - S1 * md) / (double)(T_FRAMES - 1);
    double sd = sqrt(var > 0.0 ? var : 0.0);
    float m = (float)md;
    float iv = (float)(1.0 / (sd + 1e-8));
    float cv[9];
    #pragma unroll
    for (int j = 0; j < 9; ++j)
        cv[j] = (cq[clampT(t + j - 4) * N_CQCC + k] - m) * iv;
    float dv[5];
    #pragma unroll
    for (int o = -2; o <= 2; ++o) {
        int p = clampT(t + o);
        int h1 = clampT(p + 1) - t, l1 = clampT(p - 1) - t;
        int h2 = clampT(p + 2) - t, l2 = clampT(p - 2) - t;
        dv[o + 2] = ((cv[h1 + 4] - cv[l1 + 4]) + 2.0f * (cv[h2 + 4] - cv[l2 + 4])) * 0.1f;
    }
    out[t * 60 + k]      = cv[4];
    out[t * 60 + 20 + k] = dv[2];
    out[t * 60 + 40 + k] = (dv[3] - dv[1] + 2.0f * (dv[4] - dv[0])) * 0.1f;
}

extern "C" void kernel_launch(void* const* d_in, const int* in_sizes, int n_in,
                              void* d_out, int out_size, void* d_ws, size_t ws_size,
                              hipStream_t stream) {
    const float* wav = (const float*)d_in[0];
    float* out = (float*)d_out;
    char* ws = (char*)d_ws;
    float4* QFP  = (float4*)(ws + WS_QFP);
    float2* V    = (float2*)(ws + WS_V);
    float*  cq   = (float*)(ws + WS_CQ);
    double* sums = (double*)(ws + WS_SUMS);

    k_chunk<<<dim3(NBP / BT, NF / FTW), 256, 0, stream>>>(wav, QFP);
    k_scan<<<F_COMP, 512, 0, stream>>>(QFP, V, sums);
    k_cqt<<<(T_FRAMES + TF - 1) / TF, 256, 0, stream>>>(V, cq, sums);
    k_final<<<(T_FRAMES * N_CQCC + 255) / 256, 256, 0, stream>>>(cq, sums, out);
}

// Round 9
// 101.200 us; speedup vs baseline: 1.0353x; 1.0353x over previous
//
#include <hip/hip_runtime.h>
#include <math.h>

// ---- problem constants ----
#define WAV_N     262144
#define HOP       128
#define MIN_WIN   16699
#define LEFT      24418            // (65536 - 16699)/2
#define T_FRAMES  2049
#define N_BINS    96
#define N_CQCC    20
#define F_COMP    192              // 96 bins x {lo,hi}
#define NF        576              // 192 comps x 3 Hann planes
#define NBLK      2179             // 128-sample chunks covering padded signal
#define NBP       2240             // padded b-dim for QFP rows (= 70*32)
#define PARTLEN   59               // 16699 - 130*128
#define FULLBLK   130
#define XS_VALID  278843           // 2048*128 + 16699
#define TWOPI     6.283185307179586f

// ---- chunk kernel tiling (r20): 1260 blocks (140 x 9), 256 thr = 64f x 4wg ----
// r18 broadcast-read CONFIRMED (-1.9us). r19 fold-fusion REGRESSED (+1.4us):
// 192 blocks < 256 CUs idled 1/4 of the machine, and the "saved" V traffic was
// L3-resident anyway -> inter-kernel traffic opts are worthless here; we are
// compute/latency-bound. k_scan/k_cqt reverted to r18 shape.
// r20: radix-2 decimation in k_chunk's inner loop. Q = E + W*O where E,O sum
// even/odd samples against ONE shared rotator stepping by D^2: per 2 j-steps,
// 16 essential fma + 4 rotator = 10 VALU ops/j vs r18's 12. qp (j<59, odd
// boundary) handled exactly: pairs m=0..28, lone j=58, snapshot E + D*O, lone
// j=59, pairs m=30..63. DS reads unchanged (128 uniform b128/wave).
#define BT   16
#define FTW  64
#define AST  20                    // row stride (floats); 80B rows, b128 reads 16B-aligned

// ---- workspace layout (bytes) ----
#define WS_QFP  0                  // 576*2240*16 = 20,643,840  float4(qf.re,qf.im,qp.re,qp.im)
#define WS_V    20643840           // 576*2056*8  =  9,474,048  rotated V [f][t]
#define WS_CQ   30117888           // 2049*20*4   =    163,920
#define WS_SUMS 30281808           // 40 doubles
#define VTP     2056               // V row stride (float2 units)

// f = plane*192 + c; c = bin*2 + hi; replicate reference f32 arithmetic for floor()
__device__ __forceinline__ void f_to_fi_sigma(int f, int& fi, int& sigma) {
    int plane = f / 192;
    int c = f - plane * 192;
    int bin = c >> 1, hi = c & 1;
    float e    = (float)bin / 24.0f;
    float fb   = 32.7f * exp2f(e);
    float idxf = fb / 8000.0f * 32768.0f;
    fi = (int)idxf + hi;
    sigma = (plane == 0) ? 0 : (plane == 1 ? 1 : -1);
}

__device__ __forceinline__ void make_rot(int fi, int sg, float& Dr, float& Di) {
    float fr = (float)fi * (1.0f / 65536.0f) - (float)sg * (1.0f / (float)MIN_WIN);
    fr -= rintf(fr);
    float sn, cs; __sincosf(TWOPI * fr, &sn, &cs);
    Dr = cs; Di = -sn;
}

// QFP[f][b] = (qf, qp): qf = e^{-i w0} sum_{j<128} xs[128b+j] E[j][f], qp = j<59 version
__global__ __launch_bounds__(256) void k_chunk(const float* __restrict__ wav,
                                               float4* __restrict__ QFP) {
    __shared__ __align__(16) float A_lds[128 * AST];   // 10,240 B
    int tid = threadIdx.x;
    int b0 = blockIdx.x * BT;
    int f0 = blockIdx.y * FTW;

    // stage 16b x 128j tile (256 thr x 8 elems)
    {
        int sbase = 128 * b0;
        #pragma unroll
        for (int k = 0; k < 8; ++k) {
            int m = k * 256 + tid;
            int j = m & 127, bl = m >> 7;              // bl 0..15
            int s = sbase + m;
            float v = 0.0f;
            if (s < XS_VALID) {
                int w = s - 8350;                      // s + LEFT - 32768
                if (w < 0) w = -w;
                if (w >= WAV_N) w = 2 * WAV_N - 2 - w;
                v = wav[w];
            }
            A_lds[j * AST + bl] = v;
        }
    }

    int fl = tid & 63;
    int bg = tid >> 6;                             // wave id 0..3 (uniform per wave)
    int bl0 = bg * 4;
    int bb = b0 + bl0;

    int f = f0 + fl;
    int fi, sg; f_to_fi_sigma(f, fi, sg);
    float Dr, Di; make_rot(fi, sg, Dr, Di);
    // shared radix-2 rotator: step D^2, value (W^2)^m
    float D2r = Dr * Dr - Di * Di;
    float D2i = 2.0f * Dr * Di;
    float Wr = 1.0f, Wi = 0.0f;

    float er[4] = {0,0,0,0}, ei[4] = {0,0,0,0};    // even-j accumulators
    float ur[4] = {0,0,0,0}, ui[4] = {0,0,0,0};    // odd-j accumulators (pre W^1)
    float xr[4], xi[4], pr[4], pi[4];

    __syncthreads();

    // 16 fma on two rows sharing one rotator value, then one D^2 step
    #define STEP2(a_, b_) do {                                              \
        const float aa_[4] = {(a_).x, (a_).y, (a_).z, (a_).w};              \
        const float bb_[4] = {(b_).x, (b_).y, (b_).z, (b_).w};              \
        _Pragma("unroll")                                                   \
        for (int i = 0; i < 4; ++i) {                                       \
            er[i] = fmaf(aa_[i], Wr, er[i]); ei[i] = fmaf(aa_[i], Wi, ei[i]); \
            ur[i] = fmaf(bb_[i], Wr, ur[i]); ui[i] = fmaf(bb_[i], Wi, ui[i]); \
        }                                                                   \
        float wr_ = Wr;                                                     \
        Wr = wr_ * D2r - Wi * D2i;                                          \
        Wi = wr_ * D2i + Wi * D2r; } while (0)

    #pragma unroll 2
    for (int m = 0; m < 29; ++m) {                 // j = 0..57
        float4 a = *(const float4*)&A_lds[(2 * m) * AST + bl0];
        float4 b = *(const float4*)&A_lds[(2 * m + 1) * AST + bl0];
        STEP2(a, b);
    }
    {   // j = 58 (even, uses Wv = (W^2)^29; do NOT step)
        float4 a = *(const float4*)&A_lds[58 * AST + bl0];
        const float aa_[4] = {a.x, a.y, a.z, a.w};
        #pragma unroll
        for (int i = 0; i < 4; ++i) {
            er[i] = fmaf(aa_[i], Wr, er[i]); ei[i] = fmaf(aa_[i], Wi, ei[i]);
        }
    }
    // snapshot qp = E + D*O  (evens j<=58, odds j<=57)
    #pragma unroll
    for (int i = 0; i < 4; ++i) {
        pr[i] = fmaf(Dr, ur[i], fmaf(-Di, ui[i], er[i]));
        pi[i] = fmaf(Dr, ui[i], fmaf( Di, ur[i], ei[i]));
    }
    {   // j = 59 (odd, same rotator value; then step to (W^2)^30)
        float4 b = *(const float4*)&A_lds[59 * AST + bl0];
        const float bb_[4] = {b.x, b.y, b.z, b.w};
        #pragma unroll
        for (int i = 0; i < 4; ++i) {
            ur[i] = fmaf(bb_[i], Wr, ur[i]); ui[i] = fmaf(bb_[i], Wi, ui[i]);
        }
        float wr_ = Wr;
        Wr = wr_ * D2r - Wi * D2i;
        Wi = wr_ * D2i + Wi * D2r;
    }
    #pragma unroll 2
    for (int m = 30; m < 64; ++m) {                // j = 60..127
        float4 a = *(const float4*)&A_lds[(2 * m) * AST + bl0];
        float4 b = *(const float4*)&A_lds[(2 * m + 1) * AST + bl0];
        STEP2(a, b);
    }
    // final combine qf = E + D*O
    #pragma unroll
    for (int i = 0; i < 4; ++i) {
        xr[i] = fmaf(Dr, ur[i], fmaf(-Di, ui[i], er[i]));
        xi[i] = fmaf(Dr, ui[i], fmaf( Di, ur[i], ei[i]));
    }
    #undef STEP2

    float4* dst = QFP + (size_t)f * NBP + bb;
    #pragma unroll
    for (int i = 0; i < 4; ++i) {
        int b = bb + i;
        unsigned ph = ((unsigned)fi * (unsigned)(LEFT + 128 * b)) & 65535u;
        float frf = (float)ph * (1.0f / 65536.0f)
                  - (float)sg * (float)((128 * b) % MIN_WIN) * (1.0f / (float)MIN_WIN);
        frf -= rintf(frf);
        float sn, cs; __sincosf(TWOPI * frf, &sn, &cs);
        dst[i] = make_float4(xr[i] * cs + xi[i] * sn,
                             xi[i] * cs - xr[i] * sn,
                             pr[i] * cs + pi[i] * sn,
                             pi[i] * cs - pr[i] * sn);
    }
}

// one block per f (576 blocks x 512 thr): LDS-resident float4 column, fp64 scan of
// .xy, U = G[t+130]-G[t]+qp[t+130] (qp = .zw, LDS), rotate, write V[f][t] coalesced.
#define SEG 5                      // 512*5 = 2560 >= 2179
__global__ __launch_bounds__(512) void k_scan(const float4* __restrict__ QFP,
                                              float2* __restrict__ V,
                                              double* __restrict__ sums) {
    __shared__ float4 col[NBLK];       // 34,864 B
    __shared__ double2 wsum[8];
    int tid = threadIdx.x;
    int f = blockIdx.x;
    if (f == 0 && tid < 40) sums[tid] = 0.0;   // zero stats accumulators

    const float4* g = QFP + (size_t)f * NBP;
    #pragma unroll
    for (int k = 0; k < SEG; ++k) {
        int idx = k * 512 + tid;
        if (idx < NBLK) col[idx] = g[idx];
    }
    __syncthreads();

    int s0 = tid * SEG, s1 = min(s0 + SEG, NBLK);
    double sr = 0.0, si = 0.0;
    for (int i = s0; i < s1; ++i) { sr += col[i].x; si += col[i].y; }
    double r = sr, im = si;
    #pragma unroll
    for (int off = 1; off < 64; off <<= 1) {
        double prx = __shfl_up(r, off);
        double piy = __shfl_up(im, off);
        if ((tid & 63) >= off) { r += prx; im += piy; }
    }
    if ((tid & 63) == 63) wsum[tid >> 6] = make_double2(r, im);
    __syncthreads();
    double basr = 0.0, basi = 0.0;
    int w = tid >> 6;
    for (int ww = 0; ww < w; ++ww) { basr += wsum[ww].x; basi += wsum[ww].y; }
    double gr = basr + r - sr, gi = basi + im - si;   // exclusive prefix at s0
    for (int i = s0; i < s1; ++i) {
        float qx = col[i].x, qy = col[i].y;
        col[i].x = (float)gr; col[i].y = (float)gi;
        gr += qx; gi += qy;
    }
    __syncthreads();

    int fi_, sg_; f_to_fi_sigma(f, fi_, sg_);
    float2* vrow = V + (size_t)f * VTP;
    #pragma unroll
    for (int k = 0; k < SEG; ++k) {
        int t = k * 512 + tid;
        if (t < T_FRAMES) {
            float4 ca = col[t];
            float4 cb = col[t + FULLBLK];
            float ur = cb.x - ca.x + cb.z;
            float ui = cb.y - ca.y + cb.w;
            unsigned ph = ((unsigned)fi_ * 128u * (unsigned)t) & 65535u;
            float frf = (float)ph * (1.0f / 65536.0f)
                      - (float)sg_ * (float)((128 * t) % MIN_WIN) * (1.0f / (float)MIN_WIN);
            frf -= rintf(frf);
            float sn, cs;
            __sincosf(TWOPI * frf, &sn, &cs);
            vrow[t] = make_float2(ur * cs - ui * sn, ur * sn + ui * cs);
        }
    }
}

// 8 frames/block (257 blocks): fold 3 planes (coalesced V reads along t) -> power
// -> interp -> log -> DCT -> fp64 atomic stats partials
#define TF 8
__global__ __launch_bounds__(256) void k_cqt(const float2* __restrict__ V,
                                             float* __restrict__ cq,
                                             double* __restrict__ sums) {
    __shared__ float dctm[N_CQCC * N_BINS];     // 7680 B
    __shared__ float2 sc[F_COMP * TF];          // [c][tl], 12,288 B
    __shared__ float lg[N_BINS * TF];           // [b][tl], 3072 B
    __shared__ float cqv[N_CQCC * TF];          // [k][tl], 640 B
    int tid = threadIdx.x;
    int tb = blockIdx.x * TF;
    for (int idx = tid; idx < N_CQCC * N_BINS; idx += 256) {
        int k = idx / N_BINS, b = idx - k * N_BINS;
        dctm[idx] = cosf((float)M_PI * (float)(k * (2 * b + 1)) / 192.0f);
    }
    // fold: idx = c*TF + tl; reads of V rows contiguous along t (64 B per row chunk)
    for (int idx = tid; idx < F_COMP * TF; idx += 256) {
        int c = idx / TF, tl = idx % TF;
        int t = tb + tl;
        float2 v = make_float2(0.f, 0.f);
        if (t < T_FRAMES) {
            float2 v0 = V[(size_t)c * VTP + t];
            float2 v1 = V[(size_t)(192 + c) * VTP + t];
            float2 v2 = V[(size_t)(384 + c) * VTP + t];
            v = make_float2(0.5f * v0.x - 0.25f * (v1.x + v2.x),
                            0.5f * v0.y - 0.25f * (v1.y + v2.y));
        }
        sc[idx] = v;
    }
    __syncthreads();
    for (int idx = tid; idx < N_BINS * TF; idx += 256) {
        int b = idx / TF, tl = idx % TF;
        float2 lo = sc[(2 * b) * TF + tl];
        float2 hi = sc[(2 * b + 1) * TF + tl];
        float pl = lo.x * lo.x + lo.y * lo.y;
        float ph = hi.x * hi.x + hi.y * hi.y;
        float e    = (float)b / 24.0f;
        float fb   = 32.7f * exp2f(e);
        float idxf = fb / 8000.0f * 32768.0f;
        float alpha = idxf - (float)((int)idxf);
        float p = (1.0f - alpha) * pl + alpha * ph;
        lg[idx] = logf(fmaxf(p, 1e-8f));
    }
    __syncthreads();
    for (int idx = tid; idx < N_CQCC * TF; idx += 256) {
        int k = idx / TF, tl = idx % TF;
        int t = tb + tl;
        float s = 0.0f;
        #pragma unroll 4
        for (int b = 0; b < N_BINS; ++b) s += dctm[k * N_BINS + b] * lg[b * TF + tl];
        cqv[idx] = (t < T_FRAMES) ? s : 0.0f;
        if (t < T_FRAMES) cq[t * N_CQCC + k] = s;
    }
    __syncthreads();
    if (tid < N_CQCC) {
        double s1 = 0.0, s2 = 0.0;
        #pragma unroll
        for (int tl = 0; tl < TF; ++tl) {
            if (tb + tl < T_FRAMES) {
                double v = (double)cqv[tid * TF + tl];
                s1 += v; s2 += v * v;
            }
        }
        atomicAdd(&sums[tid], s1);
        atomicAdd(&sums[N_CQCC + tid], s2);
    }
}

__device__ __forceinline__ int clampT(int v) {
    return v < 0 ? 0 : (v > T_FRAMES - 1 ? T_FRAMES - 1 : v);
}

// normalize + delta + delta-delta; mean/inv derived inline from fp64 sums
__global__ void k_final(const float* __restrict__ cq, const double* __restrict__ sums,
                        float* __restrict__ out) {
    int gid = blockIdx.x * blockDim.x + threadIdx.x;
    if (gid >= T_FRAMES * N_CQCC) return;
    int t = gid / N_CQCC;
    int k = gid - t * N_CQCC;
    double S1 = sums[k], S2 = sums[N_CQCC + k];
    double md = S1 / (double)T_FRAMES;
    double var = (S2 - S1 * md) / (double)(T_FRAMES - 1);
    double sd = sqrt(var > 0.0 ? var : 0.0);
    float m = (float)md;
    float iv = (float)(1.0 / (sd + 1e-8));
    float cv[9];
    #pragma unroll
    for (int j = 0; j < 9; ++j)
        cv[j] = (cq[clampT(t + j - 4) * N_CQCC + k] - m) * iv;
    float dv[5];
    #pragma unroll
    for (int o = -2; o <= 2; ++o) {
        int p = clampT(t + o);
        int h1 = clampT(p + 1) - t, l1 = clampT(p - 1) - t;
        int h2 = clampT(p + 2) - t, l2 = clampT(p - 2) - t;
        dv[o + 2] = ((cv[h1 + 4] - cv[l1 + 4]) + 2.0f * (cv[h2 + 4] - cv[l2 + 4])) * 0.1f;
    }
    out[t * 60 + k]      = cv[4];
    out[t * 60 + 20 + k] = dv[2];
    out[t * 60 + 40 + k] = (dv[3] - dv[1] + 2.0f * (dv[4] - dv[0])) * 0.1f;
}

extern "C" void kernel_launch(void* const* d_in, const int* in_sizes, int n_in,
                              void* d_out, int out_size, void* d_ws, size_t ws_size,
                              hipStream_t stream) {
    const float* wav = (const float*)d_in[0];
    float* out = (float*)d_out;
    char* ws = (char*)d_ws;
    float4* QFP  = (float4*)(ws + WS_QFP);
    float2* V    = (float2*)(ws + WS_V);
    float*  cq   = (float*)(ws + WS_CQ);
    double* sums = (double*)(ws + WS_SUMS);

    k_chunk<<<dim3(NBP / BT, NF / FTW), 256, 0, stream>>>(wav, QFP);
    k_scan<<<NF, 512, 0, stream>>>(QFP, V, sums);
    k_cqt<<<(T_FRAMES + TF - 1) / TF, 256, 0, stream>>>(V, cq, sums);
    k_final<<<(T_FRAMES * N_CQCC + 255) / 256, 256, 0, stream>>>(cq, sums, out);
}

// Round 10
// 100.544 us; speedup vs baseline: 1.0421x; 1.0065x over previous
//
#include <hip/hip_runtime.h>
#include <math.h>

// ---- problem constants ----
#define WAV_N     262144
#define HOP       128
#define MIN_WIN   16699
#define LEFT      24418            // (65536 - 16699)/2
#define T_FRAMES  2049
#define N_BINS    96
#define N_CQCC    20
#define F_COMP    192              // 96 bins x {lo,hi}
#define NF        576              // 192 comps x 3 Hann planes
#define NBLK      2179             // 128-sample chunks covering padded signal
#define NBP       2240             // padded b-dim for QFP rows (= 70*32)
#define PARTLEN   59               // 16699 - 130*128
#define FULLBLK   130
#define XS_VALID  278843           // 2048*128 + 16699
#define TWOPI     6.283185307179586f

// ---- chunk kernel tiling (r21): 1260 blocks (140 x 9), 256 thr = 64f x 4wg ----
// Ladder: r18 broadcast-read -1.9us; r19 fold-fusion +1.4 (L3 absorbs inter-kernel
// traffic; we are compute-bound); r20 radix-2 -2.2us (10 VALU ops/j).
// r21: radix-4 (9 ops/j): S_r = sum_m x[4m+r] (W^4)^m, one shared rotator stepping
// D^4; qf = S0 + D S1 + D^2 S2 + D^3 S3. qp boundary exact: m=0..13 full, m=14 adds
// j=56,57,58 to S0..S2, snapshot combine, j=59 into S3, m=15..31 full.
// Also: dctm (20x96 cos matrix) precomputed ONCE by block (0,0) into WS; k_cqt
// previously recomputed 1920 cosf per block x 257 blocks.
#define BT   16
#define FTW  64
#define AST  20                    // row stride (floats); 80B rows, b128 reads 16B-aligned

// ---- workspace layout (bytes) ----
#define WS_QFP  0                  // 576*2240*16 = 20,643,840  float4(qf.re,qf.im,qp.re,qp.im)
#define WS_V    20643840           // 576*2056*8  =  9,474,048  rotated V [f][t]
#define WS_CQ   30117888           // 2049*20*4   =    163,920
#define WS_SUMS 30281808           // 40 doubles
#define WS_DCT  30282368           // 20*96*4 = 7,680 (precomputed DCT matrix)
#define VTP     2056               // V row stride (float2 units)

// f = plane*192 + c; c = bin*2 + hi; replicate reference f32 arithmetic for floor()
__device__ __forceinline__ void f_to_fi_sigma(int f, int& fi, int& sigma) {
    int plane = f / 192;
    int c = f - plane * 192;
    int bin = c >> 1, hi = c & 1;
    float e    = (float)bin / 24.0f;
    float fb   = 32.7f * exp2f(e);
    float idxf = fb / 8000.0f * 32768.0f;
    fi = (int)idxf + hi;
    sigma = (plane == 0) ? 0 : (plane == 1 ? 1 : -1);
}

__device__ __forceinline__ void make_rot(int fi, int sg, float& Dr, float& Di) {
    float fr = (float)fi * (1.0f / 65536.0f) - (float)sg * (1.0f / (float)MIN_WIN);
    fr -= rintf(fr);
    float sn, cs; __sincosf(TWOPI * fr, &sn, &cs);
    Dr = cs; Di = -sn;
}

// QFP[f][b] = (qf, qp): qf = e^{-i w0} sum_{j<128} xs[128b+j] E[j][f], qp = j<59 version
__global__ __launch_bounds__(256) void k_chunk(const float* __restrict__ wav,
                                               float4* __restrict__ QFP,
                                               float* __restrict__ dct_g) {
    __shared__ __align__(16) float A_lds[128 * AST];   // 10,240 B
    int tid = threadIdx.x;
    int b0 = blockIdx.x * BT;
    int f0 = blockIdx.y * FTW;

    // stage 16b x 128j tile (256 thr x 8 elems)
    {
        int sbase = 128 * b0;
        #pragma unroll
        for (int k = 0; k < 8; ++k) {
            int m = k * 256 + tid;
            int j = m & 127, bl = m >> 7;              // bl 0..15
            int s = sbase + m;
            float v = 0.0f;
            if (s < XS_VALID) {
                int w = s - 8350;                      // s + LEFT - 32768
                if (w < 0) w = -w;
                if (w >= WAV_N) w = 2 * WAV_N - 2 - w;
                v = wav[w];
            }
            A_lds[j * AST + bl] = v;
        }
    }

    int fl = tid & 63;
    int bg = tid >> 6;                             // wave id 0..3 (uniform per wave)
    int bl0 = bg * 4;
    int bb = b0 + bl0;

    int f = f0 + fl;
    int fi, sg; f_to_fi_sigma(f, fi, sg);
    float Dr, Di; make_rot(fi, sg, Dr, Di);
    float D2r = Dr * Dr - Di * Di,    D2i = 2.0f * Dr * Di;
    float D3r = D2r * Dr - D2i * Di,  D3i = D2r * Di + D2i * Dr;
    float D4r = D2r * D2r - D2i * D2i, D4i = 2.0f * D2r * D2i;
    float Wr = 1.0f, Wi = 0.0f;                    // (W^4)^m

    float s0r[4] = {0,0,0,0}, s0i[4] = {0,0,0,0};
    float s1r[4] = {0,0,0,0}, s1i[4] = {0,0,0,0};
    float s2r[4] = {0,0,0,0}, s2i[4] = {0,0,0,0};
    float s3r[4] = {0,0,0,0}, s3i[4] = {0,0,0,0};
    float pr[4], pi[4];

    __syncthreads();

    // 32 fma on four rows sharing one rotator value, then one D^4 step
    #define STEP4(a_, b_, c_, d_) do {                                        \
        const float aa_[4] = {(a_).x, (a_).y, (a_).z, (a_).w};                \
        const float bb_[4] = {(b_).x, (b_).y, (b_).z, (b_).w};                \
        const float cc_[4] = {(c_).x, (c_).y, (c_).z, (c_).w};                \
        const float dd_[4] = {(d_).x, (d_).y, (d_).z, (d_).w};                \
        _Pragma("unroll")                                                     \
        for (int i = 0; i < 4; ++i) {                                         \
            s0r[i] = fmaf(aa_[i], Wr, s0r[i]); s0i[i] = fmaf(aa_[i], Wi, s0i[i]); \
            s1r[i] = fmaf(bb_[i], Wr, s1r[i]); s1i[i] = fmaf(bb_[i], Wi, s1i[i]); \
            s2r[i] = fmaf(cc_[i], Wr, s2r[i]); s2i[i] = fmaf(cc_[i], Wi, s2i[i]); \
            s3r[i] = fmaf(dd_[i], Wr, s3r[i]); s3i[i] = fmaf(dd_[i], Wi, s3i[i]); \
        }                                                                     \
        float wr_ = Wr;                                                       \
        Wr = wr_ * D4r - Wi * D4i;                                            \
        Wi = wr_ * D4i + Wi * D4r; } while (0)

    // combine: out = S0 + D S1 + D^2 S2 + D^3 S3 (6 fma per component)
    #define COMBINE(rr_, ii_, i_) do {                                        \
        float t1r = fmaf(Dr,  s1r[i_], fmaf(-Di,  s1i[i_], s0r[i_]));         \
        float t1i = fmaf(Dr,  s1i[i_], fmaf( Di,  s1r[i_], s0i[i_]));         \
        float t2r = fmaf(D2r, s2r[i_], fmaf(-D2i, s2i[i_], t1r));             \
        float t2i = fmaf(D2r, s2i[i_], fmaf( D2i, s2r[i_], t1i));             \
        rr_ = fmaf(D3r, s3r[i_], fmaf(-D3i, s3i[i_], t2r));                   \
        ii_ = fmaf(D3r, s3i[i_], fmaf( D3i, s3r[i_], t2i)); } while (0)

    #pragma unroll 1
    for (int m = 0; m < 14; ++m) {                 // j = 0..55
        float4 a = *(const float4*)&A_lds[(4 * m    ) * AST + bl0];
        float4 b = *(const float4*)&A_lds[(4 * m + 1) * AST + bl0];
        float4 c = *(const float4*)&A_lds[(4 * m + 2) * AST + bl0];
        float4 d = *(const float4*)&A_lds[(4 * m + 3) * AST + bl0];
        STEP4(a, b, c, d);
    }
    {   // m = 14: j = 56,57,58 (r = 0,1,2) with current W; no step yet
        float4 a = *(const float4*)&A_lds[56 * AST + bl0];
        float4 b = *(const float4*)&A_lds[57 * AST + bl0];
        float4 c = *(const float4*)&A_lds[58 * AST + bl0];
        const float aa_[4] = {a.x, a.y, a.z, a.w};
        const float bb_[4] = {b.x, b.y, b.z, b.w};
        const float cc_[4] = {c.x, c.y, c.z, c.w};
        #pragma unroll
        for (int i = 0; i < 4; ++i) {
            s0r[i] = fmaf(aa_[i], Wr, s0r[i]); s0i[i] = fmaf(aa_[i], Wi, s0i[i]);
            s1r[i] = fmaf(bb_[i], Wr, s1r[i]); s1i[i] = fmaf(bb_[i], Wi, s1i[i]);
            s2r[i] = fmaf(cc_[i], Wr, s2r[i]); s2i[i] = fmaf(cc_[i], Wi, s2i[i]);
        }
    }
    // snapshot qp (j <= 58)
    #pragma unroll
    for (int i = 0; i < 4; ++i) COMBINE(pr[i], pi[i], i);
    {   // j = 59 (r = 3) with same W; then step to (W^4)^15
        float4 d = *(const float4*)&A_lds[59 * AST + bl0];
        const float dd_[4] = {d.x, d.y, d.z, d.w};
        #pragma unroll
        for (int i = 0; i < 4; ++i) {
            s3r[i] = fmaf(dd_[i], Wr, s3r[i]); s3i[i] = fmaf(dd_[i], Wi, s3i[i]);
        }
        float wr_ = Wr;
        Wr = wr_ * D4r - Wi * D4i;
        Wi = wr_ * D4i + Wi * D4r;
    }
    #pragma unroll 1
    for (int m = 15; m < 32; ++m) {                // j = 60..127
        float4 a = *(const float4*)&A_lds[(4 * m    ) * AST + bl0];
        float4 b = *(const float4*)&A_lds[(4 * m + 1) * AST + bl0];
        float4 c = *(const float4*)&A_lds[(4 * m + 2) * AST + bl0];
        float4 d = *(const float4*)&A_lds[(4 * m + 3) * AST + bl0];
        STEP4(a, b, c, d);
    }

    float4* dst = QFP + (size_t)f * NBP + bb;
    #pragma unroll
    for (int i = 0; i < 4; ++i) {
        float qr, qi;
        COMBINE(qr, qi, i);                        // qf (j <= 127)
        int b = bb + i;
        unsigned ph = ((unsigned)fi * (unsigned)(LEFT + 128 * b)) & 65535u;
        float frf = (float)ph * (1.0f / 65536.0f)
                  - (float)sg * (float)((128 * b) % MIN_WIN) * (1.0f / (float)MIN_WIN);
        frf -= rintf(frf);
        float sn, cs; __sincosf(TWOPI * frf, &sn, &cs);
        dst[i] = make_float4(qr * cs + qi * sn,
                             qi * cs - qr * sn,
                             pr[i] * cs + pi[i] * sn,
                             pi[i] * cs - pr[i] * sn);
    }
    #undef STEP4
    #undef COMBINE

    // block (0,0): precompute DCT matrix once (off the critical path)
    if (blockIdx.x == 0 && blockIdx.y == 0) {
        for (int idx = tid; idx < N_CQCC * N_BINS; idx += 256) {
            int k = idx / N_BINS, b = idx - k * N_BINS;
            dct_g[idx] = cosf((float)M_PI * (float)(k * (2 * b + 1)) / 192.0f);
        }
    }
}

// one block per f (576 blocks x 512 thr): LDS-resident float4 column, fp64 scan of
// .xy, U = G[t+130]-G[t]+qp[t+130] (qp = .zw, LDS), rotate, write V[f][t] coalesced.
#define SEG 5                      // 512*5 = 2560 >= 2179
__global__ __launch_bounds__(512) void k_scan(const float4* __restrict__ QFP,
                                              float2* __restrict__ V,
                                              double* __restrict__ sums) {
    __shared__ float4 col[NBLK];       // 34,864 B
    __shared__ double2 wsum[8];
    int tid = threadIdx.x;
    int f = blockIdx.x;
    if (f == 0 && tid < 40) sums[tid] = 0.0;   // zero stats accumulators

    const float4* g = QFP + (size_t)f * NBP;
    #pragma unroll
    for (int k = 0; k < SEG; ++k) {
        int idx = k * 512 + tid;
        if (idx < NBLK) col[idx] = g[idx];
    }
    __syncthreads();

    int s0 = tid * SEG, s1 = min(s0 + SEG, NBLK);
    double sr = 0.0, si = 0.0;
    for (int i = s0; i < s1; ++i) { sr += col[i].x; si += col[i].y; }
    double r = sr, im = si;
    #pragma unroll
    for (int off = 1; off < 64; off <<= 1) {
        double prx = __shfl_up(r, off);
        double piy = __shfl_up(im, off);
        if ((tid & 63) >= off) { r += prx; im += piy; }
    }
    if ((tid & 63) == 63) wsum[tid >> 6] = make_double2(r, im);
    __syncthreads();
    double basr = 0.0, basi = 0.0;
    int w = tid >> 6;
    for (int ww = 0; ww < w; ++ww) { basr += wsum[ww].x; basi += wsum[ww].y; }
    double gr = basr + r - sr, gi = basi + im - si;   // exclusive prefix at s0
    for (int i = s0; i < s1; ++i) {
        float qx = col[i].x, qy = col[i].y;
        col[i].x = (float)gr; col[i].y = (float)gi;
        gr += qx; gi += qy;
    }
    __syncthreads();

    int fi_, sg_; f_to_fi_sigma(f, fi_, sg_);
    float2* vrow = V + (size_t)f * VTP;
    #pragma unroll
    for (int k = 0; k < SEG; ++k) {
        int t = k * 512 + tid;
        if (t < T_FRAMES) {
            float4 ca = col[t];
            float4 cb = col[t + FULLBLK];
            float ur = cb.x - ca.x + cb.z;
            float ui = cb.y - ca.y + cb.w;
            unsigned ph = ((unsigned)fi_ * 128u * (unsigned)t) & 65535u;
            float frf = (float)ph * (1.0f / 65536.0f)
                      - (float)sg_ * (float)((128 * t) % MIN_WIN) * (1.0f / (float)MIN_WIN);
            frf -= rintf(frf);
            float sn, cs;
            __sincosf(TWOPI * frf, &sn, &cs);
            vrow[t] = make_float2(ur * cs - ui * sn, ur * sn + ui * cs);
        }
    }
}

// 8 frames/block (257 blocks): fold 3 planes (coalesced V reads along t) -> power
// -> interp -> log -> DCT (matrix loaded from WS) -> fp64 atomic stats partials
#define TF 8
__global__ __launch_bounds__(256) void k_cqt(const float2* __restrict__ V,
                                             const float* __restrict__ dct_g,
                                             float* __restrict__ cq,
                                             double* __restrict__ sums) {
    __shared__ float dctm[N_CQCC * N_BINS];     // 7680 B
    __shared__ float2 sc[F_COMP * TF];          // [c][tl], 12,288 B
    __shared__ float lg[N_BINS * TF];           // [b][tl], 3072 B
    __shared__ float cqv[N_CQCC * TF];          // [k][tl], 640 B
    int tid = threadIdx.x;
    int tb = blockIdx.x * TF;
    for (int idx = tid; idx < N_CQCC * N_BINS; idx += 256)
        dctm[idx] = dct_g[idx];
    // fold: idx = c*TF + tl; reads of V rows contiguous along t (64 B per row chunk)
    for (int idx = tid; idx < F_COMP * TF; idx += 256) {
        int c = idx / TF, tl = idx % TF;
        int t = tb + tl;
        float2 v = make_float2(0.f, 0.f);
        if (t < T_FRAMES) {
            float2 v0 = V[(size_t)c * VTP + t];
            float2 v1 = V[(size_t)(192 + c) * VTP + t];
            float2 v2 = V[(size_t)(384 + c) * VTP + t];
            v = make_float2(0.5f * v0.x - 0.25f * (v1.x + v2.x),
                            0.5f * v0.y - 0.25f * (v1.y + v2.y));
        }
        sc[idx] = v;
    }
    __syncthreads();
    for (int idx = tid; idx < N_BINS * TF; idx += 256) {
        int b = idx / TF, tl = idx % TF;
        float2 lo = sc[(2 * b) * TF + tl];
        float2 hi = sc[(2 * b + 1) * TF + tl];
        float pl = lo.x * lo.x + lo.y * lo.y;
        float ph = hi.x * hi.x + hi.y * hi.y;
        float e    = (float)b / 24.0f;
        float fb   = 32.7f * exp2f(e);
        float idxf = fb / 8000.0f * 32768.0f;
        float alpha = idxf - (float)((int)idxf);
        float p = (1.0f - alpha) * pl + alpha * ph;
        lg[idx] = logf(fmaxf(p, 1e-8f));
    }
    __syncthreads();
    for (int idx = tid; idx < N_CQCC * TF; idx += 256) {
        int k = idx / TF, tl = idx % TF;
        int t = tb + tl;
        float s = 0.0f;
        #pragma unroll 4
        for (int b = 0; b < N_BINS; ++b) s += dctm[k * N_BINS + b] * lg[b * TF + tl];
        cqv[idx] = (t < T_FRAMES) ? s : 0.0f;
        if (t < T_FRAMES) cq[t * N_CQCC + k] = s;
    }
    __syncthreads();
    if (tid < N_CQCC) {
        double s1 = 0.0, s2 = 0.0;
        #pragma unroll
        for (int tl = 0; tl < TF; ++tl) {
            if (tb + tl < T_FRAMES) {
                double v = (double)cqv[tid * TF + tl];
                s1 += v; s2 += v * v;
            }
        }
        atomicAdd(&sums[tid], s1);
        atomicAdd(&sums[N_CQCC + tid], s2);
    }
}

__device__ __forceinline__ int clampT(int v) {
    return v < 0 ? 0 : (v > T_FRAMES - 1 ? T_FRAMES - 1 : v);
}

// normalize + delta + delta-delta; mean/inv derived inline from fp64 sums
__global__ void k_final(const float* __restrict__ cq, const double* __restrict__ sums,
                        float* __restrict__ out) {
    int gid = blockIdx.x * blockDim.x + threadIdx.x;
    if (gid >= T_FRAMES * N_CQCC) return;
    int t = gid / N_CQCC;
    int k = gid - t * N_CQCC;
    double S1 = sums[k], S2 = sums[N_CQCC + k];
    double md = S1 / (double)T_FRAMES;
    double var = (S2 - S1 * md) / (double)(T_FRAMES - 1);
    double sd = sqrt(var > 0.0 ? var : 0.0);
    float m = (float)md;
    float iv = (float)(1.0 / (sd + 1e-8));
    float cv[9];
    #pragma unroll
    for (int j = 0; j < 9; ++j)
        cv[j] = (cq[clampT(t + j - 4) * N_CQCC + k] - m) * iv;
    float dv[5];
    #pragma unroll
    for (int o = -2; o <= 2; ++o) {
        int p = clampT(t + o);
        int h1 = clampT(p + 1) - t, l1 = clampT(p - 1) - t;
        int h2 = clampT(p + 2) - t, l2 = clampT(p - 2) - t;
        dv[o + 2] = ((cv[h1 + 4] - cv[l1 + 4]) + 2.0f * (cv[h2 + 4] - cv[l2 + 4])) * 0.1f;
    }
    out[t * 60 + k]      = cv[4];
    out[t * 60 + 20 + k] = dv[2];
    out[t * 60 + 40 + k] = (dv[3] - dv[1] + 2.0f * (dv[4] - dv[0])) * 0.1f;
}

extern "C" void kernel_launch(void* const* d_in, const int* in_sizes, int n_in,
                              void* d_out, int out_size, void* d_ws, size_t ws_size,
                              hipStream_t stream) {
    const float* wav = (const float*)d_in[0];
    float* out = (float*)d_out;
    char* ws = (char*)d_ws;
    float4* QFP  = (float4*)(ws + WS_QFP);
    float2* V    = (float2*)(ws + WS_V);
    float*  cq   = (float*)(ws + WS_CQ);
    double* sums = (double*)(ws + WS_SUMS);
    float*  dct  = (float*)(ws + WS_DCT);

    k_chunk<<<dim3(NBP / BT, NF / FTW), 256, 0, stream>>>(wav, QFP, dct);
    k_scan<<<NF, 512, 0, stream>>>(QFP, V, sums);
    k_cqt<<<(T_FRAMES + TF - 1) / TF, 256, 0, stream>>>(V, dct, cq, sums);
    k_final<<<(T_FRAMES * N_CQCC + 255) / 256, 256, 0, stream>>>(cq, sums, out);
}